// Round 10
// baseline (74.386 us; speedup 1.0000x reference)
//
#include <hip/hip_runtime.h>

#define NPED 4096
#define BI 256              // threads per block (kernel A)
#define IPB 8               // pedestrians per block -> 512 blocks, 2 blocks/CU
#define EPSF 1e-8f
#define DTF 0.4f
#define INV_MASS (1.0f/60.0f)
// mag = 10 * exp((0.6 - dist)/0.71) = exp2( C0 + C1*dist )
#define C1f (-2.0319648463225964f)   // -log2(e)/0.71
#define C0f (4.54110700268092f)      // log2(10) + 0.6*log2(e)/0.71
#define NLOG2E (-1.4426950408889634f)

typedef float f2 __attribute__((ext_vector_type(2)));  // lowers to v_pk_* on gfx950

__device__ __forceinline__ float rsqf(float x) { return __builtin_amdgcn_rsqf(x); }
__device__ __forceinline__ float ex2(float x)  { return __builtin_amdgcn_exp2f(x); }

// integrate one pedestrian given summed repulsion (fx,fy raw, pre-mass)
__device__ __forceinline__ float4 integrate_one(float4 st, float2 g,
                                                float fx, float fy) {
    fx *= INV_MASS; fy *= INV_MASS;          // rf
    float tx = g.x - st.x, ty = g.y - st.y;
    float invg = rsqf(fmaf(tx, tx, fmaf(ty, ty, EPSF)));
    float Fx = fx + 2.f * fmaf(tx, invg, -st.z);   // rf + af
    float Fy = fy + 2.f * fmaf(ty, invg, -st.w);
    float npx = fmaf(0.08f, Fx, fmaf(DTF, st.z, st.x));  // 0.5*DT^2 = 0.08
    float npy = fmaf(0.08f, Fy, fmaf(DTF, st.w, st.y));
    float nvx = fmaf(DTF, Fx, st.z);
    float nvy = fmaf(DTF, Fy, st.w);
    float invs = rsqf(fmaf(nvx, nvx, fmaf(nvy, nvy, EPSF)));
    float sc = fminf(1.f, invs);             // min(1, PED_SPEED/spd)
    return make_float4(npx, npy, nvx * sc, nvy * sc);
}

// ---- Kernel A: O(N^2) repulsion, in-register reduce, integrate, write out ----
// Block b owns peds [b*8, b*8+8). 32 lanes per ped, 128 j-iters per lane.
__global__ __launch_bounds__(BI) void forces_kernel(const float4* __restrict__ state,
                                                    const float2* __restrict__ goal,
                                                    const float4* __restrict__ stk,
                                                    float* __restrict__ out) {
    __shared__ f2 spos[NPED];                // 32 KB: every position
    const int t = threadIdx.x;
    #pragma unroll
    for (int k = 0; k < NPED / BI; ++k) {    // 16 coalesced float4 loads/thread
        float4 r = state[k * BI + t];
        spos[k * BI + t] = (f2){r.x, r.y};
    }
    const int jl = t & 31;                   // j-lane within ped group
    const int i  = blockIdx.x * IPB + (t >> 5);
    float4 st = state[i];                    // 2 distinct rows/wave, broadcast-cheap
    __syncthreads();

    const f2 me = {st.x, st.y};
    f2 acc = {0.f, 0.f};
    #pragma unroll 8
    for (int k = 0; k < NPED / 32; ++k) {    // 128 iters; ds_read_b64, conflict-free
        f2 d = me - spos[(k << 5) + jl];
        float d2 = fmaf(d.x, d.x, fmaf(d.y, d.y, EPSF));
        float inv = rsqf(d2);                // 1/dist
        float dist = d2 * inv;
        float w = ex2(fmaf(dist, C1f, C0f)) * inv;   // mag/dist
        acc = d * w + acc;                   // j==i contributes exactly 0
    }
    // butterfly reduce across the 32 j-lanes (stays within each 32-lane half)
    #pragma unroll
    for (int off = 16; off > 0; off >>= 1) {
        acc.x += __shfl_xor(acc.x, off);
        acc.y += __shfl_xor(acc.y, off);
    }
    if (jl == 0) {
        float4 nw = integrate_one(st, goal[i], acc.x, acc.y);
        ((float4*)out)[i] = nw;
        // stacked = concat(stacked_in, state) at out offset N*4+1 (4B-aligned)
        float4 sv = stk[i];
        float* o1 = out + (NPED * 4 + 1) + i * 4;
        o1[0] = sv.x; o1[1] = sv.y; o1[2] = sv.z; o1[3] = sv.w;
        float* o2 = o1 + NPED * 4;
        o2[0] = st.x; o2[1] = st.y; o2[2] = st.z; o2[3] = st.w;
    }
}

// ---- Kernel B: 1-block cost epilogue. Reads new poses from out (robot = out[0..1]),
//      so no cross-block sync, no workspace, no atomics -> graph-replay safe. ----
__global__ __launch_bounds__(1024) void cost_kernel(const float4* __restrict__ state,
                                                    const float2* __restrict__ goal,
                                                    const float4* __restrict__ obs,
                                                    const float* __restrict__ cost_in,
                                                    float* __restrict__ out) {
    const int t = threadIdx.x;
    const float rx = out[0], ry = out[1];    // new robot pose (kernel-boundary ordered)
    float c = 0.f;
    #pragma unroll
    for (int k = 0; k < NPED / 1024; ++k) {  // 4 peds/thread
        const int i = (k << 10) + t;
        if (i >= 1) {
            float4 nw = ((const float4*)out)[i];
            float4 ob = obs[i];
            float dxo = nw.x - ob.x, dyo = nw.y - ob.y;
            float dev = sqrtf(fmaf(dxo, dxo, fmaf(dyo, dyo, EPSF)));
            float dxr = nw.x - rx, dyr = nw.y - ry;
            float d = sqrtf(fmaf(dxr, dxr, fmaf(dyr, dyr, EPSF)));
            c = fmaf(5.f, dev, fmaf(2.f, ex2(NLOG2E * d), c));  // A*dev + B*blame
        }
    }
    #pragma unroll
    for (int off = 32; off > 0; off >>= 1) c += __shfl_down(c, off);
    __shared__ float wsum[16];
    if ((t & 63) == 0) wsum[t >> 6] = c;
    __syncthreads();
    if (t == 0) {
        float tot = 0.f;
        #pragma unroll
        for (int w = 0; w < 16; ++w) tot += wsum[w];
        const float* stf = (const float*)state;
        const float* gf  = (const float*)goal;
        float gx = gf[0], gy = gf[1];
        float a1x = stf[0] - gx, a1y = stf[1] - gy;   // robot_init (OLD pose)
        float a2x = rx - gx,     a2y = ry - gy;       // robot new pose
        float pg = sqrtf(fmaf(a1x, a1x, fmaf(a1y, a1y, EPSF)))
                 - sqrtf(fmaf(a2x, a2x, fmaf(a2y, a2y, EPSF)));
        out[NPED * 4] = cost_in[0] + tot - pg;
    }
}

extern "C" void kernel_launch(void* const* d_in, const int* in_sizes, int n_in,
                              void* d_out, int out_size, void* d_ws, size_t ws_size,
                              hipStream_t stream) {
    const float4* state = (const float4*)d_in[0];   // (N,4)
    const float*  cost  = (const float*)d_in[1];    // (1,)
    const float4* stk   = (const float4*)d_in[2];   // (N,4)
    const float2* goal  = (const float2*)d_in[3];   // (N,2)
    const float4* obs   = (const float4*)d_in[4];   // (N,4)
    float* out = (float*)d_out;                     // N*4 | 1 | 2N*4

    forces_kernel<<<dim3(NPED / IPB), BI, 0, stream>>>(state, goal, stk, out);
    cost_kernel<<<dim3(1), 1024, 0, stream>>>(state, goal, obs, cost, out);
}